// Round 14
// baseline (120.444 us; speedup 1.0000x reference)
//
#include <hip/hip_runtime.h>

#define NH   8192
#define DIM  256
#define NTOT 16384
#define TILE 256
#define NB   64                   // NTOT / TILE
#define NTRI 2080                 // NB*(NB+1)/2
#define TBASE(R) ((R) * NB - (R) * ((R) - 1) / 2)  // row-major triangle base

constexpr float GAMMA = 0.00390625f; // 1/256

using short4v = __attribute__((ext_vector_type(4))) short;
using half8   = __attribute__((ext_vector_type(8))) _Float16;
using f32x4   = __attribute__((ext_vector_type(4))) float;

// ---------------- fused convert (fp32 -> f16) + exact fp32 row norms ----------------
__global__ void prep_kernel(const float* __restrict__ zs,
                            const float* __restrict__ zt,
                            unsigned short* __restrict__ Zf,
                            float* __restrict__ n2) {
    int w = threadIdx.x >> 6, l = threadIdx.x & 63;
    int row = blockIdx.x * 4 + w;
    const float* zp = (row < NH) ? zs + (size_t)row * DIM
                                 : zt + (size_t)(row - NH) * DIM;
    float4 v = *(const float4*)(zp + l * 4);
    float s = v.x * v.x + v.y * v.y + v.z * v.z + v.w * v.w;
#pragma unroll
    for (int off = 32; off; off >>= 1) s += __shfl_xor(s, off);
    if (l == 0) n2[row] = s;

    float x[4] = {v.x, v.y, v.z, v.w};
    short4v hv;
#pragma unroll
    for (int j = 0; j < 4; ++j) {
        _Float16 h = (_Float16)x[j];          // RNE
        hv[j] = *(short*)&h;
    }
    *(short4v*)(Zf + (size_t)row * DIM + l * 4) = hv;
}

// ---------------- main: persistent blocks, BARRIER-FREE tile loop ----------------
// A row-panel LDS-resident (barrier only on row change); B direct global->reg,
// prefetch-1; waves free-run so MFMA/VALU/LDS/VMEM pipes self-overlap.
__global__ __launch_bounds__(512, 2)
void mmd_mfma_kernel(const unsigned short* __restrict__ Zf,
                     const float* __restrict__ n2,
                     double* __restrict__ partial) {
    // A panel: 8 chunks x 8192 halves = 128 KB
    __shared__ __align__(16) unsigned short lds[65536];

    const int tid = threadIdx.x;
    const int w = tid >> 6, l = tid & 63;
    const int wr = w >> 2, wc = w & 3;   // 2x4 wave grid; wave owns 128x64
    const int fr = l & 15;               // fragment row/col within 16
    const int g  = l >> 4;               // k-group 0..3

    // XCD swizzle on block id (256 % 8 == 0); sb indexes the tile-range partition
    const int sb = ((int)blockIdx.x & 7) * 32 + ((int)blockIdx.x >> 3);
    const int start = (NTRI * sb) >> 8;
    const int end   = (NTRI * (sb + 1)) >> 8;

    // first tile (R, C), row-major triangle
    int R = 0;
    while (R < NB - 1 && TBASE(R + 1) <= start) ++R;
    int C = R + (start - TBASE(R));

    // A fragment reads: slot' = g ^ ((fr>>1)&3)   (verified conflict-free R2..R13)
    const int slotp = g ^ ((fr >> 1) & 3);
    const int aoff = (wr * 128 + fr) * 32 + slotp * 8;   // + ch*8192 + m*512

    // B global fragment row offsets (halves), per n
    int bgo[4];
#pragma unroll
    for (int n = 0; n < 4; ++n)
        bgo[n] = (wc * 64 + n * 16 + fr) * DIM + g * 8;

#define STAGE_A(GA) do {                                                              \
        _Pragma("unroll")                                                             \
        for (int ch_ = 0; ch_ < 8; ++ch_) {                                           \
            _Pragma("unroll")                                                         \
            for (int q_ = 0; q_ < 2; ++q_) {                                          \
                const int idx = q_ * 512 + tid;                                       \
                const int row_ = idx >> 2;                                            \
                const int slot_ = (idx & 3) ^ ((row_ >> 1) & 3);                      \
                const unsigned short* src = (GA) + (size_t)row_ * DIM + ch_ * 32 + slot_ * 8; \
                __builtin_amdgcn_global_load_lds(src, &lds[ch_ * 8192 + idx * 8], 16, 0, 0);  \
            }                                                                         \
        }                                                                             \
    } while (0)

#define LOADB(DST, GPTR, CH) do {                                                     \
        _Pragma("unroll")                                                             \
        for (int n_ = 0; n_ < 4; ++n_)                                                \
            DST[n_] = *(const half8*)((GPTR) + bgo[n_] + (CH) * 32);                  \
    } while (0)

    // one chunk: [prefetch next B] -> 8x{ds_read A; 4 MFMA}
#define CHUNK(CH, BQC, NXLOAD) do {                                                   \
        NXLOAD;                                                                       \
        __builtin_amdgcn_s_setprio(1);                                                \
        _Pragma("unroll")                                                             \
        for (int m_ = 0; m_ < 8; ++m_) {                                              \
            half8 aq = *(const half8*)&lds[(CH) * 8192 + aoff + m_ * 512];            \
            _Pragma("unroll")                                                         \
            for (int n_ = 0; n_ < 4; ++n_)                                            \
                acc[m_][n_] = __builtin_amdgcn_mfma_f32_16x16x32_f16(aq, BQC[n_], acc[m_][n_], 0, 0, 0); \
        }                                                                             \
        __builtin_amdgcn_s_setprio(0);                                                \
    } while (0)

    const float GL = GAMMA * 1.4426950408889634f;  // gamma*log2(e)
    const float K2 = 2.0f * GL;

    const unsigned short* gA = Zf + (size_t)R * TILE * DIM;
    const unsigned short* gB = Zf + (size_t)C * TILE * DIM;

    // row norms for row R, pre-scaled
    f32x4 ncxv[8];
#pragma unroll
    for (int m = 0; m < 8; ++m) {
        f32x4 v = *(const f32x4*)&n2[R * TILE + wr * 128 + m * 16 + g * 4];
        ncxv[m] = v * (-GL);
    }

    STAGE_A(gA);
    asm volatile("s_waitcnt vmcnt(0)" ::: "memory");
    __builtin_amdgcn_s_barrier();

    double dacc = 0.0;
    half8 bq0[4], bq1[4];
    LOADB(bq0, gB, 0);

    for (int L = start; L < end; ++L) {
        const bool lastT = (L == end - 1);
        int Rn = R, Cn = C + 1;
        if (Cn >= NB) { Rn = R + 1; Cn = Rn; }
        if (Rn > NB - 1) Rn = NB - 1;
        if (Cn > NB - 1) Cn = NB - 1;
        const unsigned short* gBn = Zf + (size_t)Cn * TILE * DIM;

        float ncy[4];
#pragma unroll
        for (int n = 0; n < 4; ++n)
            ncy[n] = -GL * n2[C * TILE + wc * 64 + n * 16 + fr];

        f32x4 acc[8][4];
#pragma unroll
        for (int m = 0; m < 8; ++m)
#pragma unroll
            for (int n = 0; n < 4; ++n) acc[m][n] = {0.f, 0.f, 0.f, 0.f};

        // 8 chunks, bq parity swaps; NO barriers — waves free-run
        CHUNK(0, bq0, LOADB(bq1, gB, 1));
        CHUNK(1, bq1, LOADB(bq0, gB, 2));
        CHUNK(2, bq0, LOADB(bq1, gB, 3));
        CHUNK(3, bq1, LOADB(bq0, gB, 4));
        CHUNK(4, bq0, LOADB(bq1, gB, 5));
        CHUNK(5, bq1, LOADB(bq0, gB, 6));
        CHUNK(6, bq0, LOADB(bq1, gB, 7));
        CHUNK(7, bq1, if (!lastT) LOADB(bq0, gBn, 0));  // next tile's chunk 0

        // ---- epilogue (regs only; next tile's B already in flight) ----
        if (R != C) {
            float fs0 = 0.f, fs1 = 0.f, fs2 = 0.f, fs3 = 0.f;
#pragma unroll
            for (int m = 0; m < 8; ++m) {
#pragma unroll
                for (int j = 0; j < 4; ++j) {
                    const float a = ncxv[m][j];
                    fs0 += __builtin_amdgcn_exp2f(fmaf(K2, acc[m][0][j], ncy[0]) + a);
                    fs1 += __builtin_amdgcn_exp2f(fmaf(K2, acc[m][1][j], ncy[1]) + a);
                    fs2 += __builtin_amdgcn_exp2f(fmaf(K2, acc[m][2][j], ncy[2]) + a);
                    fs3 += __builtin_amdgcn_exp2f(fmaf(K2, acc[m][3][j], ncy[3]) + a);
                }
            }
            const float sgn2 = ((R < 32) == (C < 32)) ? 2.0f : -2.0f;
            dacc += (double)(sgn2 * ((fs0 + fs1) + (fs2 + fs3)));
        } else {  // diagonal tile: i<j -> 2, i==j -> 1, i>j -> 0 (same half, sgn +1)
            float fsum = 0.f;
#pragma unroll
            for (int m = 0; m < 8; ++m) {
#pragma unroll
                for (int j = 0; j < 4; ++j) {
                    const int gi = R * TILE + wr * 128 + m * 16 + g * 4 + j;
#pragma unroll
                    for (int n = 0; n < 4; ++n) {
                        const int gj = C * TILE + wc * 64 + n * 16 + fr;
                        float e = __builtin_amdgcn_exp2f(fmaf(K2, acc[m][n][j], ncy[n]) + ncxv[m][j]);
                        float wgt = (gi < gj) ? 2.0f : ((gi == gj) ? 1.0f : 0.0f);
                        fsum += wgt * e;
                    }
                }
            }
            dacc += (double)fsum;
        }

        // advance; restage A + xn on row change (the only barriers in the loop)
        if (!lastT) {
            if (Rn != R) {
                __builtin_amdgcn_s_barrier();  // all waves done reading old A panel
                STAGE_A(Zf + (size_t)Rn * TILE * DIM);
#pragma unroll
                for (int m = 0; m < 8; ++m) {
                    f32x4 v = *(const f32x4*)&n2[Rn * TILE + wr * 128 + m * 16 + g * 4];
                    ncxv[m] = v * (-GL);
                }
                asm volatile("s_waitcnt vmcnt(0)" ::: "memory");
                __builtin_amdgcn_s_barrier();
            }
            R = Rn; C = Cn; gB = gBn;
        }
    }

    // block reduce: per-thread double -> per-wave -> block
#pragma unroll
    for (int off = 32; off; off >>= 1) dacc += __shfl_xor(dacc, off);
    __syncthreads();
    double* wsum = (double*)&lds[0];
    if (l == 0) wsum[w] = dacc;
    __syncthreads();
    if (tid == 0) {
        double tot = 0.0;
#pragma unroll
        for (int i = 0; i < 8; ++i) tot += wsum[i];
        partial[blockIdx.x] = tot;
    }
}

// ---------------- final reduce: 256 doubles -> scalar ----------------
__global__ void reduce_partials_kernel(const double* __restrict__ partial,
                                       float* __restrict__ out) {
    __shared__ double ws[4];
    double s = (threadIdx.x < 256) ? partial[threadIdx.x] : 0.0;
#pragma unroll
    for (int off = 32; off; off >>= 1) s += __shfl_xor(s, off);
    if ((threadIdx.x & 63) == 0) ws[threadIdx.x >> 6] = s;
    __syncthreads();
    if (threadIdx.x == 0) {
        double tot = ws[0] + ws[1] + ws[2] + ws[3];
        out[0] = (float)(tot / ((double)NH * (double)NH));
    }
}

extern "C" void kernel_launch(void* const* d_in, const int* in_sizes, int n_in,
                              void* d_out, int out_size, void* d_ws, size_t ws_size,
                              hipStream_t stream) {
    const float* zs = (const float*)d_in[0];
    const float* zt = (const float*)d_in[1];
    float* out = (float*)d_out;

    unsigned short* Zf = (unsigned short*)d_ws;                  // 8 MB (f16)
    float*  n2      = (float*)((char*)d_ws + 8388608);           // 64 KB
    double* partial = (double*)((char*)d_ws + 8454144);          // 2 KB

    prep_kernel<<<NTOT / 4, 256, 0, stream>>>(zs, zt, Zf, n2);
    mmd_mfma_kernel<<<256, 512, 0, stream>>>(Zf, n2, partial);
    reduce_partials_kernel<<<1, 256, 0, stream>>>(partial, out);
}